// Round 4
// baseline (1445.978 us; speedup 1.0000x reference)
//
#include <hip/hip_runtime.h>
#include <math.h>

#define BATCH 256
#define SEQ 512
#define SDS 54            // floats per (b,t) record: dt[6] cos[6] sin[6] Cc[18] term[18]
#define PI_F 3.14159265358979323846f

// ---- cross-lane helpers (DPP encodings verified in R3; shfl/swizzle in R1-R3) ----
template<int CTRL>
__device__ __forceinline__ float fdpp(float v) {
    return __int_as_float(__builtin_amdgcn_mov_dpp(__float_as_int(v), CTRL, 0xF, 0xF, true));
}
template<int M>
__device__ __forceinline__ float shxm(float v) {
    if constexpr (M == 1)       return fdpp<0xB1>(v);    // quad_perm xor1
    else if constexpr (M == 2)  return fdpp<0x4E>(v);    // quad_perm xor2
    else if constexpr (M == 8)  return fdpp<0x128>(v);   // row_ror:8 == xor8 in 16
    else if constexpr (M == 32) return __shfl_xor(v, 32, 64);
    else return __int_as_float(__builtin_amdgcn_ds_swizzle(__float_as_int(v), (M << 10) | 0x1F));
}
template<int L>
__device__ __forceinline__ float rdl(float v) {
    return __int_as_float(__builtin_amdgcn_readlane(__float_as_int(v), L));
}
// plain full-sum within each 32-half (depth 5: dpp,dpp,swz,dpp,swz)
__device__ __forceinline__ float sum_half(float v) {
    v += shxm<1>(v); v += shxm<2>(v); v += shxm<4>(v);
    v += shxm<8>(v); v += shxm<16>(v);
    return v;
}
// signed Walsh within each 32-half
__device__ __forceinline__ float walsh_half(float v, float g1, float g2, float g4, float g8, float g16) {
    v = fmaf(g1, v, shxm<1>(v));
    v = fmaf(g2, v, shxm<2>(v));
    v = fmaf(g4, v, shxm<4>(v));
    v = fmaf(g8, v, shxm<8>(v));
    v = fmaf(g16, v, shxm<16>(v));
    return v;
}
// QSVT per-degree CNOT-block permutation (GF(2)-linear) — verified R1-R3
__device__ __forceinline__ int permf(int x) {
    const int cs[11] = {0,1,2,3,4,5,5,4,3,2,1};
    const int ts[11] = {1,2,3,4,5,0,4,3,2,1,0};
#pragma unroll
    for (int k = 10; k >= 0; k--) {
        int cb = (x >> (5 - cs[k])) & 1;
        x ^= cb << (5 - ts[k]);
    }
    return x;
}
__device__ __forceinline__ void cmul4(const float* c,
    float vr, float vi, float ar, float ai, float br, float bi, float cr, float ci,
    float& nr, float& ni) {
    nr = c[0]*vr - c[1]*vi + c[2]*ar - c[3]*ai + c[4]*br - c[5]*bi + c[6]*cr - c[7]*ci;
    ni = c[0]*vi + c[1]*vr + c[2]*ai + c[3]*ar + c[4]*bi + c[5]*br + c[6]*ci + c[7]*cr;
}
__device__ __forceinline__ void ringapply(const float* rc,
    float vr, float vi, float br, float bi, float cr, float ci, float dr, float di,
    float& nr, float& ni) {
    nr = rc[0]*vr - rc[1]*bi - rc[2]*ci + rc[3]*dr;
    ni = rc[0]*vi + rc[1]*br + rc[2]*cr + rc[3]*di;
}

// ---------------------------------------------------------------------------
__global__ __launch_bounds__(256) void prep_kernel(
    const float* __restrict__ angles, const float* __restrict__ Wx,
    const float* __restrict__ Wdt, const float* __restrict__ bdt,
    const float* __restrict__ D, const float* __restrict__ Wc,
    float* __restrict__ sd)
{
    int gid = blockIdx.x * blockDim.x + threadIdx.x;
    if (gid >= BATCH * SEQ) return;
    const float* a = angles + (size_t)gid * 6;
    float ang[6];
#pragma unroll
    for (int i = 0; i < 6; i++) ang[i] = a[i];
    float dtr[3];
#pragma unroll
    for (int r = 0; r < 3; r++) {
        float s = 0.f;
#pragma unroll
        for (int k = 0; k < 6; k++) s += ang[k] * Wx[r * 6 + k];
        dtr[r] = s;
    }
    float* rec = sd + (size_t)gid * SDS;
    float dtv[6];
#pragma unroll
    for (int i = 0; i < 6; i++) {
        float x = bdt[i];
#pragma unroll
        for (int r = 0; r < 3; r++) x += dtr[r] * Wdt[i * 3 + r];
        float sp = (x > 15.f) ? x : log1pf(expf(x));
        dtv[i] = tanhf(sp) * PI_F;
        rec[i] = dtv[i];
        float th = ang[i] * dtv[i];        // full angle; final RY folded into meas rotation
        rec[6 + i]  = cosf(th);
        rec[12 + i] = sinf(th);
    }
    float C[6];
#pragma unroll
    for (int i = 0; i < 6; i++) {
        float s = 0.f;
#pragma unroll
        for (int k = 0; k < 6; k++) s += ang[k] * Wx[(9 + i) * 6 + k];
        C[i] = s;
    }
#pragma unroll
    for (int j = 0; j < 18; j++) {
        float s = 0.f;
#pragma unroll
        for (int i = 0; i < 6; i++) s += C[i] * Wc[j * 6 + i];
        rec[18 + j] = s;
        rec[36 + j] = D[j] * ang[j % 6];
    }
}

// ---------------------------------------------------------------------------
// umat_kernel: U[a][col] for the fixed 2-layer ansatz, via the R2-verified
// fused gate chain applied to basis state e_col. Block = col, lane = a.
// Qubit i <-> lane bit (5-i); mask of qubit i = 32>>i.
// ---------------------------------------------------------------------------
__global__ __launch_bounds__(64) void umat_kernel(const float* __restrict__ cp,
                                                  float2* __restrict__ um)
{
    const int lane = threadIdx.x;
    const int col = blockIdx.x;
    int bitv[6];
#pragma unroll
    for (int i = 0; i < 6; i++) bitv[i] = (lane >> (5 - i)) & 1;

    float qc[2][3][8], rc[2][6][4];
#pragma unroll
    for (int l = 0; l < 2; l++) {
        float g00r[6], g00i[6], g01r[6], g01i[6], g10r[6], g10i[6], g11r[6], g11i[6];
#pragma unroll
        for (int i = 0; i < 6; i++) {
            float ax = cp[l * 30 + i * 3 + 0];
            float ay = cp[l * 30 + i * 3 + 1];
            float az = cp[l * 30 + i * 3 + 2];
            float ca = cosf(0.5f * ax), sa = sinf(0.5f * ax);
            float cb = cosf(0.5f * ay), sb = sinf(0.5f * ay);
            float cg = cosf(0.5f * az), sg = sinf(0.5f * az);
            float m00r = cb * ca, m00i =  sb * sa;
            float m01r = -sb * ca, m01i = -cb * sa;
            float m10r =  sb * ca, m10i = -cb * sa;
            float m11r =  cb * ca, m11i = -sb * sa;
            g00r[i] = cg * m00r + sg * m00i; g00i[i] = cg * m00i - sg * m00r;
            g01r[i] = cg * m01r + sg * m01i; g01i[i] = cg * m01i - sg * m01r;
            g10r[i] = cg * m10r - sg * m10i; g10i[i] = cg * m10i + sg * m10r;
            g11r[i] = cg * m11r - sg * m11i; g11i[i] = cg * m11i + sg * m11r;
        }
#pragma unroll
        for (int pp = 0; pp < 3; pp++) {
            int aq = 2 * pp, bq = 2 * pp + 1;
            float dar = bitv[aq] ? g11r[aq] : g00r[aq], dai = bitv[aq] ? g11i[aq] : g00i[aq];
            float oar = bitv[aq] ? g10r[aq] : g01r[aq], oai = bitv[aq] ? g10i[aq] : g01i[aq];
            float dbr = bitv[bq] ? g11r[bq] : g00r[bq], dbi = bitv[bq] ? g11i[bq] : g00i[bq];
            float obr = bitv[bq] ? g10r[bq] : g01r[bq], obi = bitv[bq] ? g10i[bq] : g01i[bq];
            qc[l][pp][0] = dar * dbr - dai * dbi;  qc[l][pp][1] = dar * dbi + dai * dbr;
            qc[l][pp][2] = oar * dbr - oai * dbi;  qc[l][pp][3] = oar * dbi + oai * dbr;
            qc[l][pp][4] = dar * obr - dai * obi;  qc[l][pp][5] = dar * obi + dai * obr;
            qc[l][pp][6] = oar * obr - oai * obi;  qc[l][pp][7] = oar * obi + oai * obr;
        }
        const int Aq[6] = {0, 2, 4, 5, 3, 1};
        const int Bq[6] = {1, 3, 5, 4, 2, 0};
#pragma unroll
        for (int o = 0; o < 6; o++) {
            float tha = (o < 3) ? cp[l * 30 + 18 + 2 * o]     : cp[l * 30 + 24 + 2 * (o - 3)];
            float thb = (o < 3) ? cp[l * 30 + 18 + 2 * o + 1] : cp[l * 30 + 24 + 2 * (o - 3) + 1];
            float ca = cosf(0.5f * tha), sa = sinf(0.5f * tha);
            float cb = cosf(0.5f * thb), sb = sinf(0.5f * thb);
            int ba = bitv[Aq[o]], bb = bitv[Bq[o]];
            float mx0 = ba ? ca : 1.f, sae = ba ? sa : 0.f;
            float ny0 = bb ? cb : 1.f, sbe = bb ? sb : 0.f;
            rc[l][o][0] = ny0 * mx0; rc[l][o][1] = -ny0 * sae;
            rc[l][o][2] = -mx0 * sbe; rc[l][o][3] = -sae * sbe;
        }
    }

    float re = (lane == col) ? 1.f : 0.f;
    float im = 0.f;
    auto p1q = [&](int mi, int mj, const float* c) {
        float ar = __shfl_xor(re, mi, 64), ai = __shfl_xor(im, mi, 64);
        float br = __shfl_xor(re, mj, 64), bi = __shfl_xor(im, mj, 64);
        float cr = __shfl_xor(re, mi | mj, 64), ci = __shfl_xor(im, mi | mj, 64);
        float nr, ni;
        cmul4(c, re, im, ar, ai, br, bi, cr, ci, nr, ni);
        re = nr; im = ni;
    };
    auto rng = [&](int mb, int mc, const float* c) {
        float br = __shfl_xor(re, mb, 64), bi = __shfl_xor(im, mb, 64);
        float cr = __shfl_xor(re, mc, 64), ci = __shfl_xor(im, mc, 64);
        float dr = __shfl_xor(re, mb | mc, 64), di = __shfl_xor(im, mb | mc, 64);
        float nr, ni;
        ringapply(c, re, im, br, bi, cr, ci, dr, di, nr, ni);
        re = nr; im = ni;
    };
#pragma unroll
    for (int l = 0; l < 2; l++) {
        p1q(32, 16, qc[l][0]);
        p1q(8, 4, qc[l][1]);
        p1q(2, 1, qc[l][2]);
        rng(16, 8, rc[l][0]);   // (0->1)(1->2)
        rng(4, 2, rc[l][1]);    // (2->3)(3->4)
        rng(1, 32, rc[l][2]);   // (4->5)(5->0)
        rng(2, 4, rc[l][3]);    // (5->4)(4->3)
        rng(8, 16, rc[l][4]);   // (3->2)(2->1)
        rng(32, 1, rc[l][5]);   // (1->0)(0->5)
    }
    um[(size_t)lane * 64 + col] = make_float2(re, im);
}

// ---------------------------------------------------------------------------
// step_kernel: 1 wave per batch element, lane = amplitude (R2 mapping).
// Ansatz applied as dense 64x64 complex matvec from per-lane register rows.
// ---------------------------------------------------------------------------
__global__ __launch_bounds__(64, 1) void step_kernel(
    const float* __restrict__ sd, const float* __restrict__ pc,
    const float* __restrict__ qp, const float2* __restrict__ um,
    float* __restrict__ out)
{
    __shared__ float2 spsi[64];
    const int lane = threadIdx.x;
    const int b = blockIdx.x;

    int bitv[6];
#pragma unroll
    for (int i = 0; i < 6; i++) bitv[i] = (lane >> (5 - i)) & 1;
    const float g1 = (lane & 1) ? -1.f : 1.f;
    const float g2 = (lane & 2) ? -1.f : 1.f;
    const float g4 = (lane & 4) ? -1.f : 1.f;
    const float g8 = (lane & 8) ? -1.f : 1.f;
    const float g16 = (lane & 16) ? -1.f : 1.f;
    float ysg[6];
#pragma unroll
    for (int q = 0; q < 6; q++) ysg[q] = bitv[q] ? -1.f : 1.f;

    // U row into registers (one-time; L2-hot across blocks)
    float2 row[64];
#pragma unroll
    for (int j = 0; j < 64; j++) row[j] = um[(size_t)lane * 64 + j];

    // QSVT collapse: per-lane phase coefs + permuted product-state selects (R3-verified)
    float A[6], sel[6];
    {
        int x1 = permf(lane), x2 = permf(x1), x3 = permf(x2), x4 = permf(x3);
#pragma unroll
        for (int i = 0; i < 6; i++) {
            float u0 = pc[0] * PI_F * qp[0 * 6 + i];
            float u1 = pc[1] * PI_F * qp[1 * 6 + i];
            float u2 = pc[2] * PI_F * qp[2 * 6 + i];
            float u3 = pc[3] * PI_F;
            float t1 = ((x1 >> (5 - i)) & 1) ? 0.5f : -0.5f;
            float t2 = ((x2 >> (5 - i)) & 1) ? 0.5f : -0.5f;
            float t3 = ((x3 >> (5 - i)) & 1) ? 0.5f : -0.5f;
            float t4 = ((x4 >> (5 - i)) & 1) ? 0.5f : -0.5f;
            A[i] = u3 * t1 + u2 * t2 + u1 * t3 + u0 * t4;
            sel[i] = (float)((x4 >> (5 - i)) & 1);
        }
    }

    const float* sdb = sd + (size_t)b * SEQ * SDS;
    float* outb = out + (size_t)b * SEQ * 18;

    float h0 = 0.f, h1 = 0.f, h2 = 0.f, h3 = 0.f, h4 = 0.f, h5 = 0.f;
    float ysv[6];
#pragma unroll
    for (int q = 0; q < 6; q++) ysv[q] = 0.f;
    float pxm[6], pzm[6];
#pragma unroll
    for (int q = 0; q < 6; q++) { pxm[q] = 0.f; pzm[q] = 0.f; }

    for (int t = 0; t < SEQ; t++) {
        const float* r = sdb + (size_t)t * SDS;

        // ---- deferred Y(t-1) + store(t-1): off the h critical chain ----
        {
            float Y[6];
#pragma unroll
            for (int q = 0; q < 6; q++) {
                float s = sum_half(ysv[q]);
                Y[q] = rdl<0>(s) + rdl<32>(s);
            }
            if (t > 0) {
                const float* rp = sdb + (size_t)(t - 1) * SDS;
                if (lane == 0) {
                    float* o = outb + (size_t)(t - 1) * 18;
#pragma unroll
                    for (int q = 0; q < 6; q++) {
                        o[q]      = fmaf(rp[18 + q], pxm[q], rp[36 + q]);
                        o[6 + q]  = fmaf(rp[24 + q], Y[q],   rp[42 + q]);
                        o[12 + q] = fmaf(rp[30 + q], pzm[q], rp[48 + q]);
                    }
                }
            }
        }

        // ---- h-independent: QSVT phase (hoistable ahead of h arrival) ----
        float phi = A[0]*r[0] + A[1]*r[1] + A[2]*r[2] + A[3]*r[3] + A[4]*r[4] + A[5]*r[5];
        float sph, cph;
        __sincosf(phi, &sph, &cph);

        // ---- product state RY(h)|0..0>, pre-permuted via sel bits ----
        float ss0, cc0, ss1, cc1, ss2, cc2, ss3, cc3, ss4, cc4, ss5, cc5;
        __sincosf(0.5f * h0, &ss0, &cc0);
        __sincosf(0.5f * h1, &ss1, &cc1);
        __sincosf(0.5f * h2, &ss2, &cc2);
        __sincosf(0.5f * h3, &ss3, &cc3);
        __sincosf(0.5f * h4, &ss4, &cc4);
        __sincosf(0.5f * h5, &ss5, &cc5);
        float f0 = fmaf(sel[0], ss0 - cc0, cc0);
        float f1 = fmaf(sel[1], ss1 - cc1, cc1);
        float f2 = fmaf(sel[2], ss2 - cc2, cc2);
        float f3 = fmaf(sel[3], ss3 - cc3, cc3);
        float f4 = fmaf(sel[4], ss4 - cc4, cc4);
        float f5 = fmaf(sel[5], ss5 - cc5, cc5);
        float prod = ((f0 * f1) * (f2 * f3)) * (f4 * f5);
        float pr = prod * cph, pi = prod * sph;

        // ---- dense matvec: psi_post = U * psi_pre ----
        spsi[lane] = make_float2(pr, pi);
        __syncthreads();
        const float4* sp4 = (const float4*)spsi;
        float a0r = 0.f, a0i = 0.f, a1r = 0.f, a1i = 0.f;
#pragma unroll
        for (int j = 0; j < 64; j += 2) {
            float4 v = sp4[j >> 1];
            a0r = fmaf(row[j].x, v.x, a0r);
            a0r = fmaf(-row[j].y, v.y, a0r);
            a0i = fmaf(row[j].x, v.y, a0i);
            a0i = fmaf(row[j].y, v.x, a0i);
            a1r = fmaf(row[j + 1].x, v.z, a1r);
            a1r = fmaf(-row[j + 1].y, v.w, a1r);
            a1i = fmaf(row[j + 1].x, v.w, a1i);
            a1i = fmaf(row[j + 1].y, v.z, a1i);
        }
        __syncthreads();
        float re = a0r + a1r, im = a0i + a1i;

        // ---- measurements ----
        float p = re * re + im * im;
        // pair products per qubit: q (X), y (Y, pre-signed)
        float xq[6];
        {
            float rx, ix;
            rx = shxm<32>(re); ix = shxm<32>(im);
            xq[0] = re * rx + im * ix;  ysv[0] = ysg[0] * (re * ix - im * rx);
            rx = shxm<16>(re); ix = shxm<16>(im);
            xq[1] = re * rx + im * ix;  ysv[1] = ysg[1] * (re * ix - im * rx);
            rx = shxm<8>(re); ix = shxm<8>(im);
            xq[2] = re * rx + im * ix;  ysv[2] = ysg[2] * (re * ix - im * rx);
            rx = shxm<4>(re); ix = shxm<4>(im);
            xq[3] = re * rx + im * ix;  ysv[3] = ysg[3] * (re * ix - im * rx);
            rx = shxm<2>(re); ix = shxm<2>(im);
            xq[4] = re * rx + im * ix;  ysv[4] = ysg[4] * (re * ix - im * rx);
            rx = shxm<1>(re); ix = shxm<1>(im);
            xq[5] = re * rx + im * ix;  ysv[5] = ysg[5] * (re * ix - im * rx);
        }
        // Z: signed Walsh within halves; X: plain sums within halves
        float w = walsh_half(p, g1, g2, g4, g8, g16);
        float x0 = sum_half(xq[0]), x1 = sum_half(xq[1]), x2 = sum_half(xq[2]);
        float x3 = sum_half(xq[3]), x4 = sum_half(xq[4]), x5 = sum_half(xq[5]);

        // cross-half combines via readlane (SALU, no LDS stage)
        float Z0 = rdl<0>(w) - rdl<32>(w);
        float Z1 = rdl<16>(w) + rdl<48>(w);
        float Z2 = rdl<8>(w) + rdl<40>(w);
        float Z3 = rdl<4>(w) + rdl<36>(w);
        float Z4 = rdl<2>(w) + rdl<34>(w);
        float Z5 = rdl<1>(w) + rdl<33>(w);
        float X0 = rdl<0>(x0) + rdl<32>(x0);
        float X1 = rdl<0>(x1) + rdl<32>(x1);
        float X2 = rdl<0>(x2) + rdl<32>(x2);
        float X3 = rdl<0>(x3) + rdl<32>(x3);
        float X4 = rdl<0>(x4) + rdl<32>(x4);
        float X5 = rdl<0>(x5) + rdl<32>(x5);

        // folded final-RY rotation; h = rotated Z
        float ct0 = r[6], ct1 = r[7], ct2 = r[8], ct3 = r[9], ct4 = r[10], ct5 = r[11];
        float st0 = r[12], st1 = r[13], st2 = r[14], st3 = r[15], st4 = r[16], st5 = r[17];
        h0 = ct0 * Z0 - st0 * X0;
        h1 = ct1 * Z1 - st1 * X1;
        h2 = ct2 * Z2 - st2 * X2;
        h3 = ct3 * Z3 - st3 * X3;
        h4 = ct4 * Z4 - st4 * X4;
        h5 = ct5 * Z5 - st5 * X5;
        pzm[0] = h0; pzm[1] = h1; pzm[2] = h2; pzm[3] = h3; pzm[4] = h4; pzm[5] = h5;
        pxm[0] = ct0 * X0 + st0 * Z0;
        pxm[1] = ct1 * X1 + st1 * Z1;
        pxm[2] = ct2 * X2 + st2 * Z2;
        pxm[3] = ct3 * X3 + st3 * Z3;
        pxm[4] = ct4 * X4 + st4 * Z4;
        pxm[5] = ct5 * X5 + st5 * Z5;
    }

    // epilogue: deferred Y + store for t = SEQ-1
    {
        float Y[6];
#pragma unroll
        for (int q = 0; q < 6; q++) {
            float s = sum_half(ysv[q]);
            Y[q] = rdl<0>(s) + rdl<32>(s);
        }
        const float* rp = sdb + (size_t)(SEQ - 1) * SDS;
        if (lane == 0) {
            float* o = outb + (size_t)(SEQ - 1) * 18;
#pragma unroll
            for (int q = 0; q < 6; q++) {
                o[q]      = fmaf(rp[18 + q], pxm[q], rp[36 + q]);
                o[6 + q]  = fmaf(rp[24 + q], Y[q],   rp[42 + q]);
                o[12 + q] = fmaf(rp[30 + q], pzm[q], rp[48 + q]);
            }
        }
    }
}

// ---------------------------------------------------------------------------
extern "C" void kernel_launch(void* const* d_in, const int* in_sizes, int n_in,
                              void* d_out, int out_size, void* d_ws, size_t ws_size,
                              hipStream_t stream) {
    const float* angles = (const float*)d_in[0];
    const float* Wx     = (const float*)d_in[1];
    const float* Wdt    = (const float*)d_in[2];
    const float* bdt    = (const float*)d_in[3];
    const float* pc     = (const float*)d_in[4];
    const float* qp     = (const float*)d_in[5];
    const float* cp     = (const float*)d_in[6];
    const float* D      = (const float*)d_in[7];
    const float* Wc     = (const float*)d_in[8];
    float* sd  = (float*)d_ws;                           // 256*512*54*4 = 28.3 MB
    float2* um = (float2*)(sd + (size_t)BATCH * SEQ * SDS);  // +32 KB
    float* out = (float*)d_out;

    umat_kernel<<<64, 64, 0, stream>>>(cp, um);
    prep_kernel<<<(BATCH * SEQ) / 256, 256, 0, stream>>>(angles, Wx, Wdt, bdt, D, Wc, sd);
    step_kernel<<<BATCH, 64, 0, stream>>>(sd, pc, qp, um, out);
}

// Round 5
// 1198.409 us; speedup vs baseline: 1.2066x; 1.2066x over previous
//
#include <hip/hip_runtime.h>
#include <math.h>

#define BATCH 256
#define SEQ 512
#define SDS 54            // floats per (b,t) record: dt[6] cos[6] sin[6] Cc[18] term[18]
#define PI_F 3.14159265358979323846f

// ---- cross-lane helpers -----------------------------------------------------
template<int CTRL>
__device__ __forceinline__ float fdpp(float v) {
    return __int_as_float(__builtin_amdgcn_mov_dpp(__float_as_int(v), CTRL, 0xF, 0xF, true));
}
template<int L>
__device__ __forceinline__ float rdl(float v) {
    return __int_as_float(__builtin_amdgcn_readlane(__float_as_int(v), L));
}
// xor-partner gather (for pair products): 1,2 quad_perm; 8 row_ror:8(==xor8 in 16);
// 4,16 ds_swizzle; 32 shfl (ds_permute)
template<int M>
__device__ __forceinline__ float shxm(float v) {
    if constexpr (M == 1)       return fdpp<0xB1>(v);
    else if constexpr (M == 2)  return fdpp<0x4E>(v);
    else if constexpr (M == 8)  return fdpp<0x128>(v);
    else if constexpr (M == 32) return __shfl_xor(v, 32, 64);
    else return __int_as_float(__builtin_amdgcn_ds_swizzle(__float_as_int(v), (M << 10) | 0x1F));
}
// full 64-lane sum, result uniform in all lanes. Rotate-and-add within 16-rows
// (DPP row_ror — valid for commutative sum), then 4-row combine via readlane.
__device__ __forceinline__ float redsum64(float v) {
    v += fdpp<0x128>(v);   // ror8
    v += fdpp<0x124>(v);   // ror4
    v += fdpp<0x122>(v);   // ror2
    v += fdpp<0x121>(v);   // ror1  -> every lane has its 16-row sum
    return (rdl<0>(v) + rdl<16>(v)) + (rdl<32>(v) + rdl<48>(v));
}
// QSVT per-degree CNOT-block permutation (GF(2)-linear) — verified R1-R4
__device__ __forceinline__ int permf(int x) {
    const int cs[11] = {0,1,2,3,4,5,5,4,3,2,1};
    const int ts[11] = {1,2,3,4,5,0,4,3,2,1,0};
#pragma unroll
    for (int k = 10; k >= 0; k--) {
        int cb = (x >> (5 - cs[k])) & 1;
        x ^= cb << (5 - ts[k]);
    }
    return x;
}
__device__ __forceinline__ void cmul4(const float* c,
    float vr, float vi, float ar, float ai, float br, float bi, float cr, float ci,
    float& nr, float& ni) {
    nr = c[0]*vr - c[1]*vi + c[2]*ar - c[3]*ai + c[4]*br - c[5]*bi + c[6]*cr - c[7]*ci;
    ni = c[0]*vi + c[1]*vr + c[2]*ai + c[3]*ar + c[4]*bi + c[5]*br + c[6]*ci + c[7]*cr;
}
__device__ __forceinline__ void ringapply(const float* rc,
    float vr, float vi, float br, float bi, float cr, float ci, float dr, float di,
    float& nr, float& ni) {
    nr = rc[0]*vr - rc[1]*bi - rc[2]*ci + rc[3]*dr;
    ni = rc[0]*vi + rc[1]*br + rc[2]*cr + rc[3]*di;
}

// ---------------------------------------------------------------------------
__global__ __launch_bounds__(256) void prep_kernel(
    const float* __restrict__ angles, const float* __restrict__ Wx,
    const float* __restrict__ Wdt, const float* __restrict__ bdt,
    const float* __restrict__ D, const float* __restrict__ Wc,
    float* __restrict__ sd)
{
    int gid = blockIdx.x * blockDim.x + threadIdx.x;
    if (gid >= BATCH * SEQ) return;
    const float* a = angles + (size_t)gid * 6;
    float ang[6];
#pragma unroll
    for (int i = 0; i < 6; i++) ang[i] = a[i];
    float dtr[3];
#pragma unroll
    for (int r = 0; r < 3; r++) {
        float s = 0.f;
#pragma unroll
        for (int k = 0; k < 6; k++) s += ang[k] * Wx[r * 6 + k];
        dtr[r] = s;
    }
    float* rec = sd + (size_t)gid * SDS;
    float dtv[6];
#pragma unroll
    for (int i = 0; i < 6; i++) {
        float x = bdt[i];
#pragma unroll
        for (int r = 0; r < 3; r++) x += dtr[r] * Wdt[i * 3 + r];
        float sp = (x > 15.f) ? x : log1pf(expf(x));
        dtv[i] = tanhf(sp) * PI_F;
        rec[i] = dtv[i];
        float th = ang[i] * dtv[i];        // full angle; final RY folded into meas rotation
        rec[6 + i]  = cosf(th);
        rec[12 + i] = sinf(th);
    }
    float C[6];
#pragma unroll
    for (int i = 0; i < 6; i++) {
        float s = 0.f;
#pragma unroll
        for (int k = 0; k < 6; k++) s += ang[k] * Wx[(9 + i) * 6 + k];
        C[i] = s;
    }
#pragma unroll
    for (int j = 0; j < 18; j++) {
        float s = 0.f;
#pragma unroll
        for (int i = 0; i < 6; i++) s += C[i] * Wc[j * 6 + i];
        rec[18 + j] = s;
        rec[36 + j] = D[j] * ang[j % 6];
    }
}

// ---------------------------------------------------------------------------
// umat_kernel: U[a][col] for the fixed 2-layer ansatz (R2-verified gate chain
// applied to basis state e_col). Block = col, lane = a.
// ---------------------------------------------------------------------------
__global__ __launch_bounds__(64) void umat_kernel(const float* __restrict__ cp,
                                                  float2* __restrict__ um)
{
    const int lane = threadIdx.x;
    const int col = blockIdx.x;
    int bitv[6];
#pragma unroll
    for (int i = 0; i < 6; i++) bitv[i] = (lane >> (5 - i)) & 1;

    float qc[2][3][8], rc[2][6][4];
#pragma unroll
    for (int l = 0; l < 2; l++) {
        float g00r[6], g00i[6], g01r[6], g01i[6], g10r[6], g10i[6], g11r[6], g11i[6];
#pragma unroll
        for (int i = 0; i < 6; i++) {
            float ax = cp[l * 30 + i * 3 + 0];
            float ay = cp[l * 30 + i * 3 + 1];
            float az = cp[l * 30 + i * 3 + 2];
            float ca = cosf(0.5f * ax), sa = sinf(0.5f * ax);
            float cb = cosf(0.5f * ay), sb = sinf(0.5f * ay);
            float cg = cosf(0.5f * az), sg = sinf(0.5f * az);
            float m00r = cb * ca, m00i =  sb * sa;
            float m01r = -sb * ca, m01i = -cb * sa;
            float m10r =  sb * ca, m10i = -cb * sa;
            float m11r =  cb * ca, m11i = -sb * sa;
            g00r[i] = cg * m00r + sg * m00i; g00i[i] = cg * m00i - sg * m00r;
            g01r[i] = cg * m01r + sg * m01i; g01i[i] = cg * m01i - sg * m01r;
            g10r[i] = cg * m10r - sg * m10i; g10i[i] = cg * m10i + sg * m10r;
            g11r[i] = cg * m11r - sg * m11i; g11i[i] = cg * m11i + sg * m11r;
        }
#pragma unroll
        for (int pp = 0; pp < 3; pp++) {
            int aq = 2 * pp, bq = 2 * pp + 1;
            float dar = bitv[aq] ? g11r[aq] : g00r[aq], dai = bitv[aq] ? g11i[aq] : g00i[aq];
            float oar = bitv[aq] ? g10r[aq] : g01r[aq], oai = bitv[aq] ? g10i[aq] : g01i[aq];
            float dbr = bitv[bq] ? g11r[bq] : g00r[bq], dbi = bitv[bq] ? g11i[bq] : g00i[bq];
            float obr = bitv[bq] ? g10r[bq] : g01r[bq], obi = bitv[bq] ? g10i[bq] : g01i[bq];
            qc[l][pp][0] = dar * dbr - dai * dbi;  qc[l][pp][1] = dar * dbi + dai * dbr;
            qc[l][pp][2] = oar * dbr - oai * dbi;  qc[l][pp][3] = oar * dbi + oai * dbr;
            qc[l][pp][4] = dar * obr - dai * obi;  qc[l][pp][5] = dar * obi + dai * obr;
            qc[l][pp][6] = oar * obr - oai * obi;  qc[l][pp][7] = oar * obi + oai * obr;
        }
        const int Aq[6] = {0, 2, 4, 5, 3, 1};
        const int Bq[6] = {1, 3, 5, 4, 2, 0};
#pragma unroll
        for (int o = 0; o < 6; o++) {
            float tha = (o < 3) ? cp[l * 30 + 18 + 2 * o]     : cp[l * 30 + 24 + 2 * (o - 3)];
            float thb = (o < 3) ? cp[l * 30 + 18 + 2 * o + 1] : cp[l * 30 + 24 + 2 * (o - 3) + 1];
            float ca = cosf(0.5f * tha), sa = sinf(0.5f * tha);
            float cb = cosf(0.5f * thb), sb = sinf(0.5f * thb);
            int ba = bitv[Aq[o]], bb = bitv[Bq[o]];
            float mx0 = ba ? ca : 1.f, sae = ba ? sa : 0.f;
            float ny0 = bb ? cb : 1.f, sbe = bb ? sb : 0.f;
            rc[l][o][0] = ny0 * mx0; rc[l][o][1] = -ny0 * sae;
            rc[l][o][2] = -mx0 * sbe; rc[l][o][3] = -sae * sbe;
        }
    }

    float re = (lane == col) ? 1.f : 0.f;
    float im = 0.f;
    auto p1q = [&](int mi, int mj, const float* c) {
        float ar = __shfl_xor(re, mi, 64), ai = __shfl_xor(im, mi, 64);
        float br = __shfl_xor(re, mj, 64), bi = __shfl_xor(im, mj, 64);
        float cr = __shfl_xor(re, mi | mj, 64), ci = __shfl_xor(im, mi | mj, 64);
        float nr, ni;
        cmul4(c, re, im, ar, ai, br, bi, cr, ci, nr, ni);
        re = nr; im = ni;
    };
    auto rng = [&](int mb, int mc, const float* c) {
        float br = __shfl_xor(re, mb, 64), bi = __shfl_xor(im, mb, 64);
        float cr = __shfl_xor(re, mc, 64), ci = __shfl_xor(im, mc, 64);
        float dr = __shfl_xor(re, mb | mc, 64), di = __shfl_xor(im, mb | mc, 64);
        float nr, ni;
        ringapply(c, re, im, br, bi, cr, ci, dr, di, nr, ni);
        re = nr; im = ni;
    };
#pragma unroll
    for (int l = 0; l < 2; l++) {
        p1q(32, 16, qc[l][0]);
        p1q(8, 4, qc[l][1]);
        p1q(2, 1, qc[l][2]);
        rng(16, 8, rc[l][0]);
        rng(4, 2, rc[l][1]);
        rng(1, 32, rc[l][2]);
        rng(2, 4, rc[l][3]);
        rng(8, 16, rc[l][4]);
        rng(32, 1, rc[l][5]);
    }
    um[(size_t)lane * 64 + col] = make_float2(re, im);
}

// ---------------------------------------------------------------------------
// step_kernel: 1 wave per batch element, lane = amplitude.
// Dense 64x64 matvec from register rows; psi broadcast via v_readlane (no LDS,
// no barriers). All reductions DPP row_ror + readlane (no LDS).
// ---------------------------------------------------------------------------
__global__ __launch_bounds__(64, 1) void step_kernel(
    const float* __restrict__ sd, const float* __restrict__ pc,
    const float* __restrict__ qp, const float2* __restrict__ um,
    float* __restrict__ out)
{
    const int lane = threadIdx.x;
    const int b = blockIdx.x;

    int bitv[6];
#pragma unroll
    for (int i = 0; i < 6; i++) bitv[i] = (lane >> (5 - i)) & 1;
    // sign-flip masks (xor on float bits) for Z pre-signing and Y pre-signing
    int zflip[6], yflip[6];
#pragma unroll
    for (int q = 0; q < 6; q++) {
        zflip[q] = bitv[q] ? (int)0x80000000 : 0;
        yflip[q] = bitv[q] ? (int)0x80000000 : 0;   // Y sign = -1 when bit set
    }

    // U row into registers (one-time)
    float2 row[64];
#pragma unroll
    for (int j = 0; j < 64; j++) row[j] = um[(size_t)lane * 64 + j];

    // QSVT collapse: per-lane phase coefs + permuted product-state selects
    float A[6], sel[6];
    {
        int x1 = permf(lane), x2 = permf(x1), x3 = permf(x2), x4 = permf(x3);
#pragma unroll
        for (int i = 0; i < 6; i++) {
            float u0 = pc[0] * PI_F * qp[0 * 6 + i];
            float u1 = pc[1] * PI_F * qp[1 * 6 + i];
            float u2 = pc[2] * PI_F * qp[2 * 6 + i];
            float u3 = pc[3] * PI_F;
            float t1 = ((x1 >> (5 - i)) & 1) ? 0.5f : -0.5f;
            float t2 = ((x2 >> (5 - i)) & 1) ? 0.5f : -0.5f;
            float t3 = ((x3 >> (5 - i)) & 1) ? 0.5f : -0.5f;
            float t4 = ((x4 >> (5 - i)) & 1) ? 0.5f : -0.5f;
            A[i] = u3 * t1 + u2 * t2 + u1 * t3 + u0 * t4;
            sel[i] = (float)((x4 >> (5 - i)) & 1);
        }
    }

    const float* sdb = sd + (size_t)b * SEQ * SDS;
    float* outb = out + (size_t)b * SEQ * 18;

    float h0 = 0.f, h1 = 0.f, h2 = 0.f, h3 = 0.f, h4 = 0.f, h5 = 0.f;
    float ysv[6];
#pragma unroll
    for (int q = 0; q < 6; q++) ysv[q] = 0.f;
    float pxm[6], pzm[6];
#pragma unroll
    for (int q = 0; q < 6; q++) { pxm[q] = 0.f; pzm[q] = 0.f; }

    for (int t = 0; t < SEQ; t++) {
        const float* r = sdb + (size_t)t * SDS;

        // ---- deferred Y(t-1) reductions + store(t-1): off the h critical chain ----
        {
            float Y[6];
#pragma unroll
            for (int q = 0; q < 6; q++) Y[q] = redsum64(ysv[q]);
            if (t > 0 && lane == 0) {
                const float* rp = sdb + (size_t)(t - 1) * SDS;
                float* o = outb + (size_t)(t - 1) * 18;
#pragma unroll
                for (int q = 0; q < 6; q++) {
                    o[q]      = fmaf(rp[18 + q], pxm[q], rp[36 + q]);
                    o[6 + q]  = fmaf(rp[24 + q], Y[q],   rp[42 + q]);
                    o[12 + q] = fmaf(rp[30 + q], pzm[q], rp[48 + q]);
                }
            }
        }

        // ---- h-independent QSVT phase ----
        float phi = A[0]*r[0] + A[1]*r[1] + A[2]*r[2] + A[3]*r[3] + A[4]*r[4] + A[5]*r[5];
        float sph, cph;
        __sincosf(phi, &sph, &cph);

        // ---- product state RY(h)|0..0>, pre-permuted via sel bits ----
        float ss0, cc0, ss1, cc1, ss2, cc2, ss3, cc3, ss4, cc4, ss5, cc5;
        __sincosf(0.5f * h0, &ss0, &cc0);
        __sincosf(0.5f * h1, &ss1, &cc1);
        __sincosf(0.5f * h2, &ss2, &cc2);
        __sincosf(0.5f * h3, &ss3, &cc3);
        __sincosf(0.5f * h4, &ss4, &cc4);
        __sincosf(0.5f * h5, &ss5, &cc5);
        float f0 = fmaf(sel[0], ss0 - cc0, cc0);
        float f1 = fmaf(sel[1], ss1 - cc1, cc1);
        float f2 = fmaf(sel[2], ss2 - cc2, cc2);
        float f3 = fmaf(sel[3], ss3 - cc3, cc3);
        float f4 = fmaf(sel[4], ss4 - cc4, cc4);
        float f5 = fmaf(sel[5], ss5 - cc5, cc5);
        float prod = ((f0 * f1) * (f2 * f3)) * (f4 * f5);
        float pr = prod * cph, pi = prod * sph;

        // ---- dense matvec via readlane broadcast (no LDS, no barriers) ----
        float ar0 = 0.f, ai0 = 0.f, ar1 = 0.f, ai1 = 0.f;   // 4 indep chains
#pragma unroll
        for (int j = 0; j < 64; j += 2) {
            float sr0 = __int_as_float(__builtin_amdgcn_readlane(__float_as_int(pr), j));
            float si0 = __int_as_float(__builtin_amdgcn_readlane(__float_as_int(pi), j));
            float sr1 = __int_as_float(__builtin_amdgcn_readlane(__float_as_int(pr), j + 1));
            float si1 = __int_as_float(__builtin_amdgcn_readlane(__float_as_int(pi), j + 1));
            ar0 = fmaf(row[j].x, sr0, ar0);
            ar0 = fmaf(-row[j].y, si0, ar0);
            ai0 = fmaf(row[j].x, si0, ai0);
            ai0 = fmaf(row[j].y, sr0, ai0);
            ar1 = fmaf(row[j + 1].x, sr1, ar1);
            ar1 = fmaf(-row[j + 1].y, si1, ar1);
            ai1 = fmaf(row[j + 1].x, si1, ai1);
            ai1 = fmaf(row[j + 1].y, sr1, ai1);
        }
        float re = ar0 + ar1, im = ai0 + ai1;

        // ---- measurements ----
        float p = re * re + im * im;
        // pair-partner gathers (independent; 3 DPP + 2 swizzle + 1 permute)
        float pr0 = shxm<32>(re), pi0 = shxm<32>(im);   // q0
        float pr1 = shxm<16>(re), pi1 = shxm<16>(im);   // q1
        float pr2 = shxm<8>(re),  pi2 = shxm<8>(im);    // q2
        float pr3 = shxm<4>(re),  pi3 = shxm<4>(im);    // q3
        float pr4 = shxm<2>(re),  pi4 = shxm<2>(im);    // q4
        float pr5 = shxm<1>(re),  pi5 = shxm<1>(im);    // q5

        // X pair products + Y pair products (Y deferred to next iteration)
        float xq0 = re * pr0 + im * pi0;
        float xq1 = re * pr1 + im * pi1;
        float xq2 = re * pr2 + im * pi2;
        float xq3 = re * pr3 + im * pi3;
        float xq4 = re * pr4 + im * pi4;
        float xq5 = re * pr5 + im * pi5;
        ysv[0] = __int_as_float(__float_as_int(re * pi0 - im * pr0) ^ yflip[0]);
        ysv[1] = __int_as_float(__float_as_int(re * pi1 - im * pr1) ^ yflip[1]);
        ysv[2] = __int_as_float(__float_as_int(re * pi2 - im * pr2) ^ yflip[2]);
        ysv[3] = __int_as_float(__float_as_int(re * pi3 - im * pr3) ^ yflip[3]);
        ysv[4] = __int_as_float(__float_as_int(re * pi4 - im * pr4) ^ yflip[4]);
        ysv[5] = __int_as_float(__float_as_int(re * pi5 - im * pr5) ^ yflip[5]);

        // Z: pre-signed sums; X: plain sums — all DPP+readlane
        float Z0 = redsum64(__int_as_float(__float_as_int(p) ^ zflip[0]));
        float Z1 = redsum64(__int_as_float(__float_as_int(p) ^ zflip[1]));
        float Z2 = redsum64(__int_as_float(__float_as_int(p) ^ zflip[2]));
        float Z3 = redsum64(__int_as_float(__float_as_int(p) ^ zflip[3]));
        float Z4 = redsum64(__int_as_float(__float_as_int(p) ^ zflip[4]));
        float Z5 = redsum64(__int_as_float(__float_as_int(p) ^ zflip[5]));
        float X0 = redsum64(xq0);
        float X1 = redsum64(xq1);
        float X2 = redsum64(xq2);
        float X3 = redsum64(xq3);
        float X4 = redsum64(xq4);
        float X5 = redsum64(xq5);

        // folded final-RY rotation; h = rotated Z
        float ct0 = r[6], ct1 = r[7], ct2 = r[8], ct3 = r[9], ct4 = r[10], ct5 = r[11];
        float st0 = r[12], st1 = r[13], st2 = r[14], st3 = r[15], st4 = r[16], st5 = r[17];
        h0 = ct0 * Z0 - st0 * X0;
        h1 = ct1 * Z1 - st1 * X1;
        h2 = ct2 * Z2 - st2 * X2;
        h3 = ct3 * Z3 - st3 * X3;
        h4 = ct4 * Z4 - st4 * X4;
        h5 = ct5 * Z5 - st5 * X5;
        pzm[0] = h0; pzm[1] = h1; pzm[2] = h2; pzm[3] = h3; pzm[4] = h4; pzm[5] = h5;
        pxm[0] = ct0 * X0 + st0 * Z0;
        pxm[1] = ct1 * X1 + st1 * Z1;
        pxm[2] = ct2 * X2 + st2 * Z2;
        pxm[3] = ct3 * X3 + st3 * Z3;
        pxm[4] = ct4 * X4 + st4 * Z4;
        pxm[5] = ct5 * X5 + st5 * Z5;
    }

    // epilogue: deferred Y + store for t = SEQ-1
    {
        float Y[6];
#pragma unroll
        for (int q = 0; q < 6; q++) Y[q] = redsum64(ysv[q]);
        if (lane == 0) {
            const float* rp = sdb + (size_t)(SEQ - 1) * SDS;
            float* o = outb + (size_t)(SEQ - 1) * 18;
#pragma unroll
            for (int q = 0; q < 6; q++) {
                o[q]      = fmaf(rp[18 + q], pxm[q], rp[36 + q]);
                o[6 + q]  = fmaf(rp[24 + q], Y[q],   rp[42 + q]);
                o[12 + q] = fmaf(rp[30 + q], pzm[q], rp[48 + q]);
            }
        }
    }
}

// ---------------------------------------------------------------------------
extern "C" void kernel_launch(void* const* d_in, const int* in_sizes, int n_in,
                              void* d_out, int out_size, void* d_ws, size_t ws_size,
                              hipStream_t stream) {
    const float* angles = (const float*)d_in[0];
    const float* Wx     = (const float*)d_in[1];
    const float* Wdt    = (const float*)d_in[2];
    const float* bdt    = (const float*)d_in[3];
    const float* pc     = (const float*)d_in[4];
    const float* qp     = (const float*)d_in[5];
    const float* cp     = (const float*)d_in[6];
    const float* D      = (const float*)d_in[7];
    const float* Wc     = (const float*)d_in[8];
    float* sd  = (float*)d_ws;                                // 28.3 MB
    float2* um = (float2*)(sd + (size_t)BATCH * SEQ * SDS);   // +32 KB
    float* out = (float*)d_out;

    umat_kernel<<<64, 64, 0, stream>>>(cp, um);
    prep_kernel<<<(BATCH * SEQ) / 256, 256, 0, stream>>>(angles, Wx, Wdt, bdt, D, Wc, sd);
    step_kernel<<<BATCH, 64, 0, stream>>>(sd, pc, qp, um, out);
}

// Round 6
// 728.154 us; speedup vs baseline: 1.9858x; 1.6458x over previous
//
#include <hip/hip_runtime.h>
#include <math.h>

#define BATCH 256
#define SEQ 512
#define SDS 54            // floats per (b,t) record: dt[6] cos[6] sin[6] Cc[18] term[18]
#define PI_F 3.14159265358979323846f

// ---- cross-lane helpers -----------------------------------------------------
template<int CTRL>
__device__ __forceinline__ float fdpp(float v) {
    return __int_as_float(__builtin_amdgcn_mov_dpp(__float_as_int(v), CTRL, 0xF, 0xF, true));
}
template<int L>
__device__ __forceinline__ float rdl(float v) {
    return __int_as_float(__builtin_amdgcn_readlane(__float_as_int(v), L));
}
__device__ __forceinline__ float rdlv(float v, int l) {   // uniform (SGPR) lane index
    return __int_as_float(__builtin_amdgcn_readlane(__float_as_int(v), l));
}
// xor-partner gather within a wave: 1,2 quad_perm DPP; 8 row_ror:8; 4,16 ds_swizzle; 32 shfl
template<int M>
__device__ __forceinline__ float shxm(float v) {
    if constexpr (M == 1)       return fdpp<0xB1>(v);
    else if constexpr (M == 2)  return fdpp<0x4E>(v);
    else if constexpr (M == 8)  return fdpp<0x128>(v);
    else if constexpr (M == 32) return __shfl_xor(v, 32, 64);
    else return __int_as_float(__builtin_amdgcn_ds_swizzle(__float_as_int(v), (M << 10) | 0x1F));
}
// full 64-lane sum (uniform result): DPP row_ror rotate-adds + readlane combine
__device__ __forceinline__ float redsum64(float v) {
    v += fdpp<0x128>(v);
    v += fdpp<0x124>(v);
    v += fdpp<0x122>(v);
    v += fdpp<0x121>(v);
    return (rdl<0>(v) + rdl<16>(v)) + (rdl<32>(v) + rdl<48>(v));
}
__device__ __forceinline__ float xorf(float v, int m) {
    return __int_as_float(__float_as_int(v) ^ m);
}
// QSVT per-degree CNOT-block permutation (GF(2)-linear) — verified R1-R5
__device__ __forceinline__ int permf(int x) {
    const int cs[11] = {0,1,2,3,4,5,5,4,3,2,1};
    const int ts[11] = {1,2,3,4,5,0,4,3,2,1,0};
#pragma unroll
    for (int k = 10; k >= 0; k--) {
        int cb = (x >> (5 - cs[k])) & 1;
        x ^= cb << (5 - ts[k]);
    }
    return x;
}
__device__ __forceinline__ void cmul4(const float* c,
    float vr, float vi, float ar, float ai, float br, float bi, float cr, float ci,
    float& nr, float& ni) {
    nr = c[0]*vr - c[1]*vi + c[2]*ar - c[3]*ai + c[4]*br - c[5]*bi + c[6]*cr - c[7]*ci;
    ni = c[0]*vi + c[1]*vr + c[2]*ai + c[3]*ar + c[4]*bi + c[5]*br + c[6]*ci + c[7]*cr;
}
__device__ __forceinline__ void ringapply(const float* rc,
    float vr, float vi, float br, float bi, float cr, float ci, float dr, float di,
    float& nr, float& ni) {
    nr = rc[0]*vr - rc[1]*bi - rc[2]*ci + rc[3]*dr;
    ni = rc[0]*vi + rc[1]*br + rc[2]*cr + rc[3]*di;
}

// ---------------------------------------------------------------------------
__global__ __launch_bounds__(256) void prep_kernel(
    const float* __restrict__ angles, const float* __restrict__ Wx,
    const float* __restrict__ Wdt, const float* __restrict__ bdt,
    const float* __restrict__ D, const float* __restrict__ Wc,
    float* __restrict__ sd)
{
    int gid = blockIdx.x * blockDim.x + threadIdx.x;
    if (gid >= BATCH * SEQ) return;
    const float* a = angles + (size_t)gid * 6;
    float ang[6];
#pragma unroll
    for (int i = 0; i < 6; i++) ang[i] = a[i];
    float dtr[3];
#pragma unroll
    for (int r = 0; r < 3; r++) {
        float s = 0.f;
#pragma unroll
        for (int k = 0; k < 6; k++) s += ang[k] * Wx[r * 6 + k];
        dtr[r] = s;
    }
    float* rec = sd + (size_t)gid * SDS;
    float dtv[6];
#pragma unroll
    for (int i = 0; i < 6; i++) {
        float x = bdt[i];
#pragma unroll
        for (int r = 0; r < 3; r++) x += dtr[r] * Wdt[i * 3 + r];
        float sp = (x > 15.f) ? x : log1pf(expf(x));
        dtv[i] = tanhf(sp) * PI_F;
        rec[i] = dtv[i];
        float th = ang[i] * dtv[i];        // full angle; final RY folded into meas rotation
        rec[6 + i]  = cosf(th);
        rec[12 + i] = sinf(th);
    }
    float C[6];
#pragma unroll
    for (int i = 0; i < 6; i++) {
        float s = 0.f;
#pragma unroll
        for (int k = 0; k < 6; k++) s += ang[k] * Wx[(9 + i) * 6 + k];
        C[i] = s;
    }
#pragma unroll
    for (int j = 0; j < 18; j++) {
        float s = 0.f;
#pragma unroll
        for (int i = 0; i < 6; i++) s += C[i] * Wc[j * 6 + i];
        rec[18 + j] = s;
        rec[36 + j] = D[j] * ang[j % 6];
    }
}

// ---------------------------------------------------------------------------
// umat_kernel: U[a][col] for the fixed 2-layer ansatz (R2-verified gate chain).
// ---------------------------------------------------------------------------
__global__ __launch_bounds__(64) void umat_kernel(const float* __restrict__ cp,
                                                  float2* __restrict__ um)
{
    const int lane = threadIdx.x;
    const int col = blockIdx.x;
    int bitv[6];
#pragma unroll
    for (int i = 0; i < 6; i++) bitv[i] = (lane >> (5 - i)) & 1;

    float qc[2][3][8], rc[2][6][4];
#pragma unroll
    for (int l = 0; l < 2; l++) {
        float g00r[6], g00i[6], g01r[6], g01i[6], g10r[6], g10i[6], g11r[6], g11i[6];
#pragma unroll
        for (int i = 0; i < 6; i++) {
            float ax = cp[l * 30 + i * 3 + 0];
            float ay = cp[l * 30 + i * 3 + 1];
            float az = cp[l * 30 + i * 3 + 2];
            float ca = cosf(0.5f * ax), sa = sinf(0.5f * ax);
            float cb = cosf(0.5f * ay), sb = sinf(0.5f * ay);
            float cg = cosf(0.5f * az), sg = sinf(0.5f * az);
            float m00r = cb * ca, m00i =  sb * sa;
            float m01r = -sb * ca, m01i = -cb * sa;
            float m10r =  sb * ca, m10i = -cb * sa;
            float m11r =  cb * ca, m11i = -sb * sa;
            g00r[i] = cg * m00r + sg * m00i; g00i[i] = cg * m00i - sg * m00r;
            g01r[i] = cg * m01r + sg * m01i; g01i[i] = cg * m01i - sg * m01r;
            g10r[i] = cg * m10r - sg * m10i; g10i[i] = cg * m10i + sg * m10r;
            g11r[i] = cg * m11r - sg * m11i; g11i[i] = cg * m11i + sg * m11r;
        }
#pragma unroll
        for (int pp = 0; pp < 3; pp++) {
            int aq = 2 * pp, bq = 2 * pp + 1;
            float dar = bitv[aq] ? g11r[aq] : g00r[aq], dai = bitv[aq] ? g11i[aq] : g00i[aq];
            float oar = bitv[aq] ? g10r[aq] : g01r[aq], oai = bitv[aq] ? g10i[aq] : g01i[aq];
            float dbr = bitv[bq] ? g11r[bq] : g00r[bq], dbi = bitv[bq] ? g11i[bq] : g00i[bq];
            float obr = bitv[bq] ? g10r[bq] : g01r[bq], obi = bitv[bq] ? g10i[bq] : g01i[bq];
            qc[l][pp][0] = dar * dbr - dai * dbi;  qc[l][pp][1] = dar * dbi + dai * dbr;
            qc[l][pp][2] = oar * dbr - oai * dbi;  qc[l][pp][3] = oar * dbi + oai * dbr;
            qc[l][pp][4] = dar * obr - dai * obi;  qc[l][pp][5] = dar * obi + dai * obr;
            qc[l][pp][6] = oar * obr - oai * obi;  qc[l][pp][7] = oar * obi + oai * obr;
        }
        const int Aq[6] = {0, 2, 4, 5, 3, 1};
        const int Bq[6] = {1, 3, 5, 4, 2, 0};
#pragma unroll
        for (int o = 0; o < 6; o++) {
            float tha = (o < 3) ? cp[l * 30 + 18 + 2 * o]     : cp[l * 30 + 24 + 2 * (o - 3)];
            float thb = (o < 3) ? cp[l * 30 + 18 + 2 * o + 1] : cp[l * 30 + 24 + 2 * (o - 3) + 1];
            float ca = cosf(0.5f * tha), sa = sinf(0.5f * tha);
            float cb = cosf(0.5f * thb), sb = sinf(0.5f * thb);
            int ba = bitv[Aq[o]], bb = bitv[Bq[o]];
            float mx0 = ba ? ca : 1.f, sae = ba ? sa : 0.f;
            float ny0 = bb ? cb : 1.f, sbe = bb ? sb : 0.f;
            rc[l][o][0] = ny0 * mx0; rc[l][o][1] = -ny0 * sae;
            rc[l][o][2] = -mx0 * sbe; rc[l][o][3] = -sae * sbe;
        }
    }

    float re = (lane == col) ? 1.f : 0.f;
    float im = 0.f;
    auto p1q = [&](int mi, int mj, const float* c) {
        float ar = __shfl_xor(re, mi, 64), ai = __shfl_xor(im, mi, 64);
        float br = __shfl_xor(re, mj, 64), bi = __shfl_xor(im, mj, 64);
        float cr = __shfl_xor(re, mi | mj, 64), ci = __shfl_xor(im, mi | mj, 64);
        float nr, ni;
        cmul4(c, re, im, ar, ai, br, bi, cr, ci, nr, ni);
        re = nr; im = ni;
    };
    auto rng = [&](int mb, int mc, const float* c) {
        float br = __shfl_xor(re, mb, 64), bi = __shfl_xor(im, mb, 64);
        float cr = __shfl_xor(re, mc, 64), ci = __shfl_xor(im, mc, 64);
        float dr = __shfl_xor(re, mb | mc, 64), di = __shfl_xor(im, mb | mc, 64);
        float nr, ni;
        ringapply(c, re, im, br, bi, cr, ci, dr, di, nr, ni);
        re = nr; im = ni;
    };
#pragma unroll
    for (int l = 0; l < 2; l++) {
        p1q(32, 16, qc[l][0]);
        p1q(8, 4, qc[l][1]);
        p1q(2, 1, qc[l][2]);
        rng(16, 8, rc[l][0]);
        rng(4, 2, rc[l][1]);
        rng(1, 32, rc[l][2]);
        rng(2, 4, rc[l][3]);
        rng(8, 16, rc[l][4]);
        rng(32, 1, rc[l][5]);
    }
    um[(size_t)lane * 64 + col] = make_float2(re, im);
}

// ---------------------------------------------------------------------------
// step_kernel: 4 waves (256 threads) per batch element — one per SIMD.
// Every wave holds the full lane=amp image. Matvec split by columns (16/wave);
// reductions split by wave; two barriers/step exchange partials and scalars.
// ---------------------------------------------------------------------------
__global__ __launch_bounds__(256, 1) void step_kernel(
    const float* __restrict__ sd, const float* __restrict__ pc,
    const float* __restrict__ qp, const float2* __restrict__ um,
    float* __restrict__ out)
{
    __shared__ float2 sPart[4][64];
    __shared__ float sZX[12];    // Z0..5, X0..5
    __shared__ float sY[6];
    const int tid = threadIdx.x;
    const int wave = tid >> 6;
    const int lane = tid & 63;
    const int b = blockIdx.x;

    int bitv[6];
#pragma unroll
    for (int i = 0; i < 6; i++) bitv[i] = (lane >> (5 - i)) & 1;
    int sflip[6];
#pragma unroll
    for (int q = 0; q < 6; q++) sflip[q] = bitv[q] ? (int)0x80000000 : 0;

    // U column-chunk rows: wave w owns columns [16w, 16w+16)
    const int jbase = wave * 16;
    float2 row[16];
#pragma unroll
    for (int jj = 0; jj < 16; jj++) row[jj] = um[(size_t)lane * 64 + jbase + jj];

    // QSVT collapse: per-lane phase coefs + permuted product-state selects
    float A[6], sel[6];
    {
        int x1 = permf(lane), x2 = permf(x1), x3 = permf(x2), x4 = permf(x3);
#pragma unroll
        for (int i = 0; i < 6; i++) {
            float u0 = pc[0] * PI_F * qp[0 * 6 + i];
            float u1 = pc[1] * PI_F * qp[1 * 6 + i];
            float u2 = pc[2] * PI_F * qp[2 * 6 + i];
            float u3 = pc[3] * PI_F;
            float t1 = ((x1 >> (5 - i)) & 1) ? 0.5f : -0.5f;
            float t2 = ((x2 >> (5 - i)) & 1) ? 0.5f : -0.5f;
            float t3 = ((x3 >> (5 - i)) & 1) ? 0.5f : -0.5f;
            float t4 = ((x4 >> (5 - i)) & 1) ? 0.5f : -0.5f;
            A[i] = u3 * t1 + u2 * t2 + u1 * t3 + u0 * t4;
            sel[i] = (float)((x4 >> (5 - i)) & 1);
        }
    }

    const float* sdb = sd + (size_t)b * SEQ * SDS;
    float* outb = out + (size_t)b * SEQ * 18;

    float h0 = 0.f, h1 = 0.f, h2 = 0.f, h3 = 0.f, h4 = 0.f, h5 = 0.f;

    for (int t = 0; t < SEQ; t++) {
        const float* r = sdb + (size_t)t * SDS;
        // loads needed by all waves (hoisted early; compiler schedules)
        float d0 = r[0], d1 = r[1], d2 = r[2], d3 = r[3], d4 = r[4], d5 = r[5];
        float ct[6], st[6];
#pragma unroll
        for (int q = 0; q < 6; q++) { ct[q] = r[6 + q]; st[q] = r[12 + q]; }

        // ---- QSVT phase (h-independent) ----
        float phi = A[0]*d0 + A[1]*d1 + A[2]*d2 + A[3]*d3 + A[4]*d4 + A[5]*d5;
        float sph, cph;
        __sincosf(phi, &sph, &cph);

        // ---- product state RY(h)|0..0>, pre-permuted via sel bits ----
        float ss0, cc0, ss1, cc1, ss2, cc2, ss3, cc3, ss4, cc4, ss5, cc5;
        __sincosf(0.5f * h0, &ss0, &cc0);
        __sincosf(0.5f * h1, &ss1, &cc1);
        __sincosf(0.5f * h2, &ss2, &cc2);
        __sincosf(0.5f * h3, &ss3, &cc3);
        __sincosf(0.5f * h4, &ss4, &cc4);
        __sincosf(0.5f * h5, &ss5, &cc5);
        float f0 = fmaf(sel[0], ss0 - cc0, cc0);
        float f1 = fmaf(sel[1], ss1 - cc1, cc1);
        float f2 = fmaf(sel[2], ss2 - cc2, cc2);
        float f3 = fmaf(sel[3], ss3 - cc3, cc3);
        float f4 = fmaf(sel[4], ss4 - cc4, cc4);
        float f5 = fmaf(sel[5], ss5 - cc5, cc5);
        float prod = ((f0 * f1) * (f2 * f3)) * (f4 * f5);
        float pr = prod * cph, pi = prod * sph;

        // ---- partial matvec over this wave's 16 columns ----
        float ar0 = 0.f, ai0 = 0.f, ar1 = 0.f, ai1 = 0.f;
#pragma unroll
        for (int jj = 0; jj < 16; jj += 2) {
            float sr0 = rdlv(pr, jbase + jj);
            float si0 = rdlv(pi, jbase + jj);
            float sr1 = rdlv(pr, jbase + jj + 1);
            float si1 = rdlv(pi, jbase + jj + 1);
            ar0 = fmaf(row[jj].x, sr0, ar0);
            ar0 = fmaf(-row[jj].y, si0, ar0);
            ai0 = fmaf(row[jj].x, si0, ai0);
            ai0 = fmaf(row[jj].y, sr0, ai0);
            ar1 = fmaf(row[jj + 1].x, sr1, ar1);
            ar1 = fmaf(-row[jj + 1].y, si1, ar1);
            ai1 = fmaf(row[jj + 1].x, si1, ai1);
            ai1 = fmaf(row[jj + 1].y, sr1, ai1);
        }
        sPart[wave][lane] = make_float2(ar0 + ar1, ai0 + ai1);
        __syncthreads();   // barrier A
        float2 q0v = sPart[0][lane], q1v = sPart[1][lane];
        float2 q2v = sPart[2][lane], q3v = sPart[3][lane];
        float re = (q0v.x + q1v.x) + (q2v.x + q3v.x);
        float im = (q0v.y + q1v.y) + (q2v.y + q3v.y);

        // ---- split reductions ----
        if (wave == 0) {
            float p = re * re + im * im;
            float Z0 = redsum64(xorf(p, sflip[0]));
            float Z1 = redsum64(xorf(p, sflip[1]));
            float Z2 = redsum64(xorf(p, sflip[2]));
            float Z3 = redsum64(xorf(p, sflip[3]));
            float Z4 = redsum64(xorf(p, sflip[4]));
            float Z5 = redsum64(xorf(p, sflip[5]));
            if (lane == 0) {
                sZX[0] = Z0; sZX[1] = Z1; sZX[2] = Z2;
                sZX[3] = Z3; sZX[4] = Z4; sZX[5] = Z5;
            }
        } else if (wave == 1) {
            float g0r = shxm<32>(re), g0i = shxm<32>(im);   // q0
            float g1r = shxm<16>(re), g1i = shxm<16>(im);   // q1
            float g2r = shxm<8>(re),  g2i = shxm<8>(im);    // q2
            float X0 = redsum64(re * g0r + im * g0i);
            float X1 = redsum64(re * g1r + im * g1i);
            float X2 = redsum64(re * g2r + im * g2i);
            float Y0 = redsum64(xorf(re * g0i - im * g0r, sflip[0]));
            float Y1 = redsum64(xorf(re * g1i - im * g1r, sflip[1]));
            float Y2 = redsum64(xorf(re * g2i - im * g2r, sflip[2]));
            if (lane == 0) {
                sZX[6] = X0; sZX[7] = X1; sZX[8] = X2;
                sY[0] = Y0; sY[1] = Y1; sY[2] = Y2;
            }
        } else if (wave == 2) {
            float g3r = shxm<4>(re), g3i = shxm<4>(im);     // q3
            float g4r = shxm<2>(re), g4i = shxm<2>(im);     // q4
            float g5r = shxm<1>(re), g5i = shxm<1>(im);     // q5
            float X3 = redsum64(re * g3r + im * g3i);
            float X4 = redsum64(re * g4r + im * g4i);
            float X5 = redsum64(re * g5r + im * g5i);
            float Y3 = redsum64(xorf(re * g3i - im * g3r, sflip[3]));
            float Y4 = redsum64(xorf(re * g4i - im * g4r, sflip[4]));
            float Y5 = redsum64(xorf(re * g5i - im * g5r, sflip[5]));
            if (lane == 0) {
                sZX[9] = X3; sZX[10] = X4; sZX[11] = X5;
                sY[3] = Y3; sY[4] = Y4; sY[5] = Y5;
            }
        }
        __syncthreads();   // barrier B

        // ---- all waves: read scalars, assemble h (uniform-address broadcast) ----
        float Zv[6], Xv[6];
#pragma unroll
        for (int q = 0; q < 6; q++) { Zv[q] = sZX[q]; Xv[q] = sZX[6 + q]; }
        h0 = ct[0] * Zv[0] - st[0] * Xv[0];
        h1 = ct[1] * Zv[1] - st[1] * Xv[1];
        h2 = ct[2] * Zv[2] - st[2] * Xv[2];
        h3 = ct[3] * Zv[3] - st[3] * Xv[3];
        h4 = ct[4] * Zv[4] - st[4] * Xv[4];
        h5 = ct[5] * Zv[5] - st[5] * Xv[5];

        // ---- stores (off the h critical path; w0 takes Z-outs, w3 takes X/Y-outs) ----
        if (wave == 0 && lane == 0) {
            float* o = outb + (size_t)t * 18;
            float hh[6] = {h0, h1, h2, h3, h4, h5};
#pragma unroll
            for (int q = 0; q < 6; q++) o[12 + q] = fmaf(r[30 + q], hh[q], r[48 + q]);
        }
        if (wave == 3 && lane == 0) {
            float* o = outb + (size_t)t * 18;
#pragma unroll
            for (int q = 0; q < 6; q++) {
                float px = ct[q] * Xv[q] + st[q] * Zv[q];
                o[q]     = fmaf(r[18 + q], px, r[36 + q]);
                o[6 + q] = fmaf(r[24 + q], sY[q], r[42 + q]);
            }
        }
    }
}

// ---------------------------------------------------------------------------
extern "C" void kernel_launch(void* const* d_in, const int* in_sizes, int n_in,
                              void* d_out, int out_size, void* d_ws, size_t ws_size,
                              hipStream_t stream) {
    const float* angles = (const float*)d_in[0];
    const float* Wx     = (const float*)d_in[1];
    const float* Wdt    = (const float*)d_in[2];
    const float* bdt    = (const float*)d_in[3];
    const float* pc     = (const float*)d_in[4];
    const float* qp     = (const float*)d_in[5];
    const float* cp     = (const float*)d_in[6];
    const float* D      = (const float*)d_in[7];
    const float* Wc     = (const float*)d_in[8];
    float* sd  = (float*)d_ws;                                // 28.3 MB
    float2* um = (float2*)(sd + (size_t)BATCH * SEQ * SDS);   // +32 KB
    float* out = (float*)d_out;

    umat_kernel<<<64, 64, 0, stream>>>(cp, um);
    prep_kernel<<<(BATCH * SEQ) / 256, 256, 0, stream>>>(angles, Wx, Wdt, bdt, D, Wc, sd);
    step_kernel<<<BATCH, 256, 0, stream>>>(sd, pc, qp, um, out);
}

// Round 7
// 712.802 us; speedup vs baseline: 2.0286x; 1.0215x over previous
//
#include <hip/hip_runtime.h>
#include <math.h>

#define BATCH 256
#define SEQ 512
#define SDS 54            // floats per (b,t) record: dt[6] cos[6] sin[6] Cc[18] term[18]
#define PI_F 3.14159265358979323846f

// ---- cross-lane helpers -----------------------------------------------------
template<int CTRL>
__device__ __forceinline__ float fdpp(float v) {
    return __int_as_float(__builtin_amdgcn_mov_dpp(__float_as_int(v), CTRL, 0xF, 0xF, true));
}
template<int L>
__device__ __forceinline__ float rdl(float v) {
    return __int_as_float(__builtin_amdgcn_readlane(__float_as_int(v), L));
}
__device__ __forceinline__ float rdlv(float v, int l) {
    return __int_as_float(__builtin_amdgcn_readlane(__float_as_int(v), l));
}
template<int M>
__device__ __forceinline__ float shxm(float v) {
    if constexpr (M == 1)       return fdpp<0xB1>(v);
    else if constexpr (M == 2)  return fdpp<0x4E>(v);
    else if constexpr (M == 8)  return fdpp<0x128>(v);
    else if constexpr (M == 32) return __shfl_xor(v, 32, 64);
    else return __int_as_float(__builtin_amdgcn_ds_swizzle(__float_as_int(v), (M << 10) | 0x1F));
}
// full 64-lane sum (uniform result): DPP row_ror rotate-adds + readlane combine
__device__ __forceinline__ float redsum64(float v) {
    v += fdpp<0x128>(v);
    v += fdpp<0x124>(v);
    v += fdpp<0x122>(v);
    v += fdpp<0x121>(v);
    return (rdl<0>(v) + rdl<16>(v)) + (rdl<32>(v) + rdl<48>(v));
}
__device__ __forceinline__ float xorf(float v, int m) {
    return __int_as_float(__float_as_int(v) ^ m);
}
// Workgroup barrier WITHOUT vmcnt drain: LDS-only visibility (lgkmcnt(0)),
// global loads stay in flight, stores fire-and-forget.
// 0xC07F = vmcnt(63) expcnt(7) lgkmcnt(0) in gfx9 encoding.
__device__ __forceinline__ void wg_barrier_lds() {
    __builtin_amdgcn_sched_barrier(0);
    __builtin_amdgcn_s_waitcnt(0xC07F);
    __builtin_amdgcn_s_barrier();
    __builtin_amdgcn_sched_barrier(0);
}
// QSVT per-degree CNOT-block permutation (GF(2)-linear) — verified R1-R6
__device__ __forceinline__ int permf(int x) {
    const int cs[11] = {0,1,2,3,4,5,5,4,3,2,1};
    const int ts[11] = {1,2,3,4,5,0,4,3,2,1,0};
#pragma unroll
    for (int k = 10; k >= 0; k--) {
        int cb = (x >> (5 - cs[k])) & 1;
        x ^= cb << (5 - ts[k]);
    }
    return x;
}
__device__ __forceinline__ void cmul4(const float* c,
    float vr, float vi, float ar, float ai, float br, float bi, float cr, float ci,
    float& nr, float& ni) {
    nr = c[0]*vr - c[1]*vi + c[2]*ar - c[3]*ai + c[4]*br - c[5]*bi + c[6]*cr - c[7]*ci;
    ni = c[0]*vi + c[1]*vr + c[2]*ai + c[3]*ar + c[4]*bi + c[5]*br + c[6]*ci + c[7]*cr;
}
__device__ __forceinline__ void ringapply(const float* rc,
    float vr, float vi, float br, float bi, float cr, float ci, float dr, float di,
    float& nr, float& ni) {
    nr = rc[0]*vr - rc[1]*bi - rc[2]*ci + rc[3]*dr;
    ni = rc[0]*vi + rc[1]*br + rc[2]*cr + rc[3]*di;
}

// ---------------------------------------------------------------------------
__global__ __launch_bounds__(256) void prep_kernel(
    const float* __restrict__ angles, const float* __restrict__ Wx,
    const float* __restrict__ Wdt, const float* __restrict__ bdt,
    const float* __restrict__ D, const float* __restrict__ Wc,
    float* __restrict__ sd)
{
    int gid = blockIdx.x * blockDim.x + threadIdx.x;
    if (gid >= BATCH * SEQ) return;
    const float* a = angles + (size_t)gid * 6;
    float ang[6];
#pragma unroll
    for (int i = 0; i < 6; i++) ang[i] = a[i];
    float dtr[3];
#pragma unroll
    for (int r = 0; r < 3; r++) {
        float s = 0.f;
#pragma unroll
        for (int k = 0; k < 6; k++) s += ang[k] * Wx[r * 6 + k];
        dtr[r] = s;
    }
    float* rec = sd + (size_t)gid * SDS;
    float dtv[6];
#pragma unroll
    for (int i = 0; i < 6; i++) {
        float x = bdt[i];
#pragma unroll
        for (int r = 0; r < 3; r++) x += dtr[r] * Wdt[i * 3 + r];
        float sp = (x > 15.f) ? x : log1pf(expf(x));
        dtv[i] = tanhf(sp) * PI_F;
        rec[i] = dtv[i];
        float th = ang[i] * dtv[i];
        rec[6 + i]  = cosf(th);
        rec[12 + i] = sinf(th);
    }
    float C[6];
#pragma unroll
    for (int i = 0; i < 6; i++) {
        float s = 0.f;
#pragma unroll
        for (int k = 0; k < 6; k++) s += ang[k] * Wx[(9 + i) * 6 + k];
        C[i] = s;
    }
#pragma unroll
    for (int j = 0; j < 18; j++) {
        float s = 0.f;
#pragma unroll
        for (int i = 0; i < 6; i++) s += C[i] * Wc[j * 6 + i];
        rec[18 + j] = s;
        rec[36 + j] = D[j] * ang[j % 6];
    }
}

// ---------------------------------------------------------------------------
// umat_kernel: U[a][col] for the fixed 2-layer ansatz (R2-verified gate chain).
// ---------------------------------------------------------------------------
__global__ __launch_bounds__(64) void umat_kernel(const float* __restrict__ cp,
                                                  float2* __restrict__ um)
{
    const int lane = threadIdx.x;
    const int col = blockIdx.x;
    int bitv[6];
#pragma unroll
    for (int i = 0; i < 6; i++) bitv[i] = (lane >> (5 - i)) & 1;

    float qc[2][3][8], rc[2][6][4];
#pragma unroll
    for (int l = 0; l < 2; l++) {
        float g00r[6], g00i[6], g01r[6], g01i[6], g10r[6], g10i[6], g11r[6], g11i[6];
#pragma unroll
        for (int i = 0; i < 6; i++) {
            float ax = cp[l * 30 + i * 3 + 0];
            float ay = cp[l * 30 + i * 3 + 1];
            float az = cp[l * 30 + i * 3 + 2];
            float ca = cosf(0.5f * ax), sa = sinf(0.5f * ax);
            float cb = cosf(0.5f * ay), sb = sinf(0.5f * ay);
            float cg = cosf(0.5f * az), sg = sinf(0.5f * az);
            float m00r = cb * ca, m00i =  sb * sa;
            float m01r = -sb * ca, m01i = -cb * sa;
            float m10r =  sb * ca, m10i = -cb * sa;
            float m11r =  cb * ca, m11i = -sb * sa;
            g00r[i] = cg * m00r + sg * m00i; g00i[i] = cg * m00i - sg * m00r;
            g01r[i] = cg * m01r + sg * m01i; g01i[i] = cg * m01i - sg * m01r;
            g10r[i] = cg * m10r - sg * m10i; g10i[i] = cg * m10i + sg * m10r;
            g11r[i] = cg * m11r - sg * m11i; g11i[i] = cg * m11i + sg * m11r;
        }
#pragma unroll
        for (int pp = 0; pp < 3; pp++) {
            int aq = 2 * pp, bq = 2 * pp + 1;
            float dar = bitv[aq] ? g11r[aq] : g00r[aq], dai = bitv[aq] ? g11i[aq] : g00i[aq];
            float oar = bitv[aq] ? g10r[aq] : g01r[aq], oai = bitv[aq] ? g10i[aq] : g01i[aq];
            float dbr = bitv[bq] ? g11r[bq] : g00r[bq], dbi = bitv[bq] ? g11i[bq] : g00i[bq];
            float obr = bitv[bq] ? g10r[bq] : g01r[bq], obi = bitv[bq] ? g10i[bq] : g01i[bq];
            qc[l][pp][0] = dar * dbr - dai * dbi;  qc[l][pp][1] = dar * dbi + dai * dbr;
            qc[l][pp][2] = oar * dbr - oai * dbi;  qc[l][pp][3] = oar * dbi + oai * dbr;
            qc[l][pp][4] = dar * obr - dai * obi;  qc[l][pp][5] = dar * obi + dai * obr;
            qc[l][pp][6] = oar * obr - oai * obi;  qc[l][pp][7] = oar * obi + oai * obr;
        }
        const int Aq[6] = {0, 2, 4, 5, 3, 1};
        const int Bq[6] = {1, 3, 5, 4, 2, 0};
#pragma unroll
        for (int o = 0; o < 6; o++) {
            float tha = (o < 3) ? cp[l * 30 + 18 + 2 * o]     : cp[l * 30 + 24 + 2 * (o - 3)];
            float thb = (o < 3) ? cp[l * 30 + 18 + 2 * o + 1] : cp[l * 30 + 24 + 2 * (o - 3) + 1];
            float ca = cosf(0.5f * tha), sa = sinf(0.5f * tha);
            float cb = cosf(0.5f * thb), sb = sinf(0.5f * thb);
            int ba = bitv[Aq[o]], bb = bitv[Bq[o]];
            float mx0 = ba ? ca : 1.f, sae = ba ? sa : 0.f;
            float ny0 = bb ? cb : 1.f, sbe = bb ? sb : 0.f;
            rc[l][o][0] = ny0 * mx0; rc[l][o][1] = -ny0 * sae;
            rc[l][o][2] = -mx0 * sbe; rc[l][o][3] = -sae * sbe;
        }
    }

    float re = (lane == col) ? 1.f : 0.f;
    float im = 0.f;
    auto p1q = [&](int mi, int mj, const float* c) {
        float ar = __shfl_xor(re, mi, 64), ai = __shfl_xor(im, mi, 64);
        float br = __shfl_xor(re, mj, 64), bi = __shfl_xor(im, mj, 64);
        float cr = __shfl_xor(re, mi | mj, 64), ci = __shfl_xor(im, mi | mj, 64);
        float nr, ni;
        cmul4(c, re, im, ar, ai, br, bi, cr, ci, nr, ni);
        re = nr; im = ni;
    };
    auto rng = [&](int mb, int mc, const float* c) {
        float br = __shfl_xor(re, mb, 64), bi = __shfl_xor(im, mb, 64);
        float cr = __shfl_xor(re, mc, 64), ci = __shfl_xor(im, mc, 64);
        float dr = __shfl_xor(re, mb | mc, 64), di = __shfl_xor(im, mb | mc, 64);
        float nr, ni;
        ringapply(c, re, im, br, bi, cr, ci, dr, di, nr, ni);
        re = nr; im = ni;
    };
#pragma unroll
    for (int l = 0; l < 2; l++) {
        p1q(32, 16, qc[l][0]);
        p1q(8, 4, qc[l][1]);
        p1q(2, 1, qc[l][2]);
        rng(16, 8, rc[l][0]);
        rng(4, 2, rc[l][1]);
        rng(1, 32, rc[l][2]);
        rng(2, 4, rc[l][3]);
        rng(8, 16, rc[l][4]);
        rng(32, 1, rc[l][5]);
    }
    um[(size_t)lane * 64 + col] = make_float2(re, im);
}

// ---------------------------------------------------------------------------
// step_kernel: 4 waves per batch element (one per SIMD). Matvec split by
// columns; reductions split by qubit across waves; two LDS-only barriers/step
// (no vmcnt drain); record loads software-pipelined one step ahead.
// ---------------------------------------------------------------------------
__global__ __launch_bounds__(256, 1) void step_kernel(
    const float* __restrict__ sd, const float* __restrict__ pc,
    const float* __restrict__ qp, const float2* __restrict__ um,
    float* __restrict__ out)
{
    __shared__ float2 sPart[4][64];
    __shared__ __align__(16) float sZXY[20];   // Z0..5, X0..5, Y0..5 (+pad)
    const int tid = threadIdx.x;
    const int wave = tid >> 6;
    const int lane = tid & 63;
    const int b = blockIdx.x;

    int bitv[6];
#pragma unroll
    for (int i = 0; i < 6; i++) bitv[i] = (lane >> (5 - i)) & 1;
    int sflip[6];
#pragma unroll
    for (int q = 0; q < 6; q++) sflip[q] = bitv[q] ? (int)0x80000000 : 0;

    // U column-chunk rows: wave w owns columns [16w, 16w+16)
    const int jbase = wave * 16;
    float2 row[16];
#pragma unroll
    for (int jj = 0; jj < 16; jj++) row[jj] = um[(size_t)lane * 64 + jbase + jj];

    // QSVT collapse: per-lane phase coefs + permuted product-state selects
    float A[6], sel[6];
    {
        int x1 = permf(lane), x2 = permf(x1), x3 = permf(x2), x4 = permf(x3);
#pragma unroll
        for (int i = 0; i < 6; i++) {
            float u0 = pc[0] * PI_F * qp[0 * 6 + i];
            float u1 = pc[1] * PI_F * qp[1 * 6 + i];
            float u2 = pc[2] * PI_F * qp[2 * 6 + i];
            float u3 = pc[3] * PI_F;
            float t1 = ((x1 >> (5 - i)) & 1) ? 0.5f : -0.5f;
            float t2 = ((x2 >> (5 - i)) & 1) ? 0.5f : -0.5f;
            float t3 = ((x3 >> (5 - i)) & 1) ? 0.5f : -0.5f;
            float t4 = ((x4 >> (5 - i)) & 1) ? 0.5f : -0.5f;
            A[i] = u3 * t1 + u2 * t2 + u1 * t3 + u0 * t4;
            sel[i] = (float)((x4 >> (5 - i)) & 1);
        }
    }

    const float* sdb = sd + (size_t)b * SEQ * SDS;
    float* outb = out + (size_t)b * SEQ * 18;

    float h0 = 0.f, h1 = 0.f, h2 = 0.f, h3 = 0.f, h4 = 0.f, h5 = 0.f;

    // software-pipelined record fields: d[6], ct[6], st[6]
    float cd[18], nd[18];
#pragma unroll
    for (int k = 0; k < 18; k++) cd[k] = sdb[k];

    for (int t = 0; t < SEQ; t++) {
        const float* r  = sdb + (size_t)t * SDS;
        const float* rn = sdb + (size_t)((t + 1 < SEQ) ? t + 1 : t) * SDS;
        // prefetch next record (stays in flight across the whole step:
        // barriers below do NOT drain vmcnt)
#pragma unroll
        for (int k = 0; k < 18; k++) nd[k] = rn[k];

        // ---- QSVT phase (h-independent) ----
        float phi = A[0]*cd[0] + A[1]*cd[1] + A[2]*cd[2] + A[3]*cd[3] + A[4]*cd[4] + A[5]*cd[5];
        float sph, cph;
        __sincosf(phi, &sph, &cph);

        // ---- product state RY(h)|0..0>, pre-permuted via sel bits ----
        float ss0, cc0, ss1, cc1, ss2, cc2, ss3, cc3, ss4, cc4, ss5, cc5;
        __sincosf(0.5f * h0, &ss0, &cc0);
        __sincosf(0.5f * h1, &ss1, &cc1);
        __sincosf(0.5f * h2, &ss2, &cc2);
        __sincosf(0.5f * h3, &ss3, &cc3);
        __sincosf(0.5f * h4, &ss4, &cc4);
        __sincosf(0.5f * h5, &ss5, &cc5);
        float f0 = fmaf(sel[0], ss0 - cc0, cc0);
        float f1 = fmaf(sel[1], ss1 - cc1, cc1);
        float f2 = fmaf(sel[2], ss2 - cc2, cc2);
        float f3 = fmaf(sel[3], ss3 - cc3, cc3);
        float f4 = fmaf(sel[4], ss4 - cc4, cc4);
        float f5 = fmaf(sel[5], ss5 - cc5, cc5);
        float prod = ((f0 * f1) * (f2 * f3)) * (f4 * f5);
        float pr = prod * cph, pi = prod * sph;

        // ---- partial matvec over this wave's 16 columns ----
        float ar0 = 0.f, ai0 = 0.f, ar1 = 0.f, ai1 = 0.f;
#pragma unroll
        for (int jj = 0; jj < 16; jj += 2) {
            float sr0 = rdlv(pr, jbase + jj);
            float si0 = rdlv(pi, jbase + jj);
            float sr1 = rdlv(pr, jbase + jj + 1);
            float si1 = rdlv(pi, jbase + jj + 1);
            ar0 = fmaf(row[jj].x, sr0, ar0);
            ar0 = fmaf(-row[jj].y, si0, ar0);
            ai0 = fmaf(row[jj].x, si0, ai0);
            ai0 = fmaf(row[jj].y, sr0, ai0);
            ar1 = fmaf(row[jj + 1].x, sr1, ar1);
            ar1 = fmaf(-row[jj + 1].y, si1, ar1);
            ai1 = fmaf(row[jj + 1].x, si1, ai1);
            ai1 = fmaf(row[jj + 1].y, sr1, ai1);
        }
        sPart[wave][lane] = make_float2(ar0 + ar1, ai0 + ai1);
        wg_barrier_lds();   // barrier A (LDS-only drain)
        float2 q0v = sPart[0][lane], q1v = sPart[1][lane];
        float2 q2v = sPart[2][lane], q3v = sPart[3][lane];
        float re = (q0v.x + q1v.x) + (q2v.x + q3v.x);
        float im = (q0v.y + q1v.y) + (q2v.y + q3v.y);

        // ---- reductions split by qubit across waves ----
        if (wave == 0) {
            float p = re * re + im * im;
            float Z0 = redsum64(xorf(p, sflip[0]));
            float Z1 = redsum64(xorf(p, sflip[1]));
            float Z2 = redsum64(xorf(p, sflip[2]));
            float Z3 = redsum64(xorf(p, sflip[3]));
            float Z4 = redsum64(xorf(p, sflip[4]));
            float Z5 = redsum64(xorf(p, sflip[5]));
            if (lane == 0) {
                sZXY[0] = Z0; sZXY[1] = Z1; sZXY[2] = Z2;
                sZXY[3] = Z3; sZXY[4] = Z4; sZXY[5] = Z5;
            }
        } else if (wave == 1) {
            float g0r = shxm<32>(re), g0i = shxm<32>(im);   // q0
            float g1r = shxm<16>(re), g1i = shxm<16>(im);   // q1
            float X0 = redsum64(re * g0r + im * g0i);
            float X1 = redsum64(re * g1r + im * g1i);
            float Y0 = redsum64(xorf(re * g0i - im * g0r, sflip[0]));
            float Y1 = redsum64(xorf(re * g1i - im * g1r, sflip[1]));
            if (lane == 0) { sZXY[6] = X0; sZXY[7] = X1; sZXY[12] = Y0; sZXY[13] = Y1; }
        } else if (wave == 2) {
            float g2r = shxm<8>(re), g2i = shxm<8>(im);     // q2
            float g3r = shxm<4>(re), g3i = shxm<4>(im);     // q3
            float X2 = redsum64(re * g2r + im * g2i);
            float X3 = redsum64(re * g3r + im * g3i);
            float Y2 = redsum64(xorf(re * g2i - im * g2r, sflip[2]));
            float Y3 = redsum64(xorf(re * g3i - im * g3r, sflip[3]));
            if (lane == 0) { sZXY[8] = X2; sZXY[9] = X3; sZXY[14] = Y2; sZXY[15] = Y3; }
        } else {
            float g4r = shxm<2>(re), g4i = shxm<2>(im);     // q4
            float g5r = shxm<1>(re), g5i = shxm<1>(im);     // q5
            float X4 = redsum64(re * g4r + im * g4i);
            float X5 = redsum64(re * g5r + im * g5i);
            float Y4 = redsum64(xorf(re * g4i - im * g4r, sflip[4]));
            float Y5 = redsum64(xorf(re * g5i - im * g5r, sflip[5]));
            if (lane == 0) { sZXY[10] = X4; sZXY[11] = X5; sZXY[16] = Y4; sZXY[17] = Y5; }
        }
        wg_barrier_lds();   // barrier B (LDS-only drain)

        // ---- all waves: vectorized scalar broadcast, assemble h ----
        float4 v0 = ((const float4*)sZXY)[0];   // Z0..Z3
        float4 v1 = ((const float4*)sZXY)[1];   // Z4 Z5 X0 X1
        float4 v2 = ((const float4*)sZXY)[2];   // X2..X5
        float Zv[6] = {v0.x, v0.y, v0.z, v0.w, v1.x, v1.y};
        float Xv[6] = {v1.z, v1.w, v2.x, v2.y, v2.z, v2.w};
        h0 = cd[6]  * Zv[0] - cd[12] * Xv[0];
        h1 = cd[7]  * Zv[1] - cd[13] * Xv[1];
        h2 = cd[8]  * Zv[2] - cd[14] * Xv[2];
        h3 = cd[9]  * Zv[3] - cd[15] * Xv[3];
        h4 = cd[10] * Zv[4] - cd[16] * Xv[4];
        h5 = cd[11] * Zv[5] - cd[17] * Xv[5];

        // ---- stores (global, fire-and-forget; never drained by barriers) ----
        if (wave == 0 && lane == 0) {
            float* o = outb + (size_t)t * 18;
            float hh[6] = {h0, h1, h2, h3, h4, h5};
#pragma unroll
            for (int q = 0; q < 6; q++) o[12 + q] = fmaf(r[30 + q], hh[q], r[48 + q]);
        }
        if (wave == 3 && lane == 0) {
            float* o = outb + (size_t)t * 18;
#pragma unroll
            for (int q = 0; q < 6; q++) {
                float px = cd[6 + q] * Xv[q] + cd[12 + q] * Zv[q];
                o[q]     = fmaf(r[18 + q], px, r[36 + q]);
                o[6 + q] = fmaf(r[24 + q], sZXY[12 + q], r[42 + q]);
            }
        }

        // rotate pipelined record
#pragma unroll
        for (int k = 0; k < 18; k++) cd[k] = nd[k];
    }
}

// ---------------------------------------------------------------------------
extern "C" void kernel_launch(void* const* d_in, const int* in_sizes, int n_in,
                              void* d_out, int out_size, void* d_ws, size_t ws_size,
                              hipStream_t stream) {
    const float* angles = (const float*)d_in[0];
    const float* Wx     = (const float*)d_in[1];
    const float* Wdt    = (const float*)d_in[2];
    const float* bdt    = (const float*)d_in[3];
    const float* pc     = (const float*)d_in[4];
    const float* qp     = (const float*)d_in[5];
    const float* cp     = (const float*)d_in[6];
    const float* D      = (const float*)d_in[7];
    const float* Wc     = (const float*)d_in[8];
    float* sd  = (float*)d_ws;                                // 28.3 MB
    float2* um = (float2*)(sd + (size_t)BATCH * SEQ * SDS);   // +32 KB
    float* out = (float*)d_out;

    umat_kernel<<<64, 64, 0, stream>>>(cp, um);
    prep_kernel<<<(BATCH * SEQ) / 256, 256, 0, stream>>>(angles, Wx, Wdt, bdt, D, Wc, sd);
    step_kernel<<<BATCH, 256, 0, stream>>>(sd, pc, qp, um, out);
}